// Round 1
// 300.029 us; speedup vs baseline: 1.0447x; 1.0447x over previous
//
#include <hip/hip_runtime.h>

#define BB 2
#define NN 4096
#define CIN 128
#define CC 64

typedef __attribute__((ext_vector_type(4))) float floatx4;
typedef __attribute__((ext_vector_type(8))) short short8;

__device__ __forceinline__ short f2bf(float f) {
    unsigned u = __float_as_uint(f);
    u += 0x7fffu + ((u >> 16) & 1u);   // RNE
    return (short)(u >> 16);
}

// sigmoid via v_exp_f32 + v_rcp_f32 (avoid precise-division expansion)
__device__ __forceinline__ float sigf(float x) {
    return __builtin_amdgcn_rcpf(1.0f + __expf(-x));
}

// ---------------------------------------------------------------------------
// feat_v3: h = relu(relu(x@W1+b1)@W2+b2); u,v scalars; hT bf16 transposed.
// 16 rows/block, 256 threads (16 rows x 16 cgroups x 4 ch), grid 512.
// hT now written via LDS transpose tile -> coalesced short8 stores
// (was: per-lane 2B stores at 32KB stride -> partial-line RMW storm).
// ---------------------------------------------------------------------------
__global__ __launch_bounds__(256) void feat_v3(
    const float* __restrict__ x, const float* __restrict__ W1,
    const float* __restrict__ b1, const float* __restrict__ W2,
    const float* __restrict__ b2, const float* __restrict__ Wa,
    const float* __restrict__ ba,
    short* __restrict__ hT, float* __restrict__ u, float* __restrict__ v)
{
    __shared__ float W1s[CIN * CC];      // 32KB
    __shared__ float W2s[CC * CC];       // 16KB
    __shared__ float xs[16 * 132];       // 8.4KB padded
    __shared__ float h1s[16 * 68];       // 4.4KB padded
    __shared__ __align__(16) short hs[CC][16];  // 2KB bf16 transpose tile

    const int t = threadIdx.x;
    const int row0 = blockIdx.x * 16;

    {
        const floatx4* s1 = (const floatx4*)W1;
        floatx4* d1 = (floatx4*)W1s;
        for (int i = t; i < CIN * CC / 4; i += 256) d1[i] = s1[i];
        const floatx4* s2 = (const floatx4*)W2;
        floatx4* d2 = (floatx4*)W2s;
        for (int i = t; i < CC * CC / 4; i += 256) d2[i] = s2[i];
        const floatx4* sx = (const floatx4*)(x + (size_t)row0 * CIN);
        for (int i = t; i < 16 * CIN / 4; i += 256) {
            int rw = i >> 5, c4 = i & 31;
            *(floatx4*)(xs + rw * 132 + c4 * 4) = sx[i];
        }
    }
    __syncthreads();

    const int n  = t >> 4;       // 0..15 local row
    const int cg = t & 15;
    const int c0 = cg * 4;

    float acc[4];
#pragma unroll
    for (int i = 0; i < 4; i++) acc[i] = b1[c0 + i];
    for (int k = 0; k < CIN; k++) {
        float a = xs[n * 132 + k];
        const floatx4 w = *(const floatx4*)&W1s[k * CC + c0];
#pragma unroll
        for (int i = 0; i < 4; i++) acc[i] = fmaf(a, w[i], acc[i]);
    }
#pragma unroll
    for (int i = 0; i < 4; i++) h1s[n * 68 + c0 + i] = fmaxf(acc[i], 0.0f);
    __syncthreads();

    float acc2[4];
#pragma unroll
    for (int i = 0; i < 4; i++) acc2[i] = b2[c0 + i];
    for (int k = 0; k < CC; k++) {
        float a = h1s[n * 68 + k];
        const floatx4 w = *(const floatx4*)&W2s[k * CC + c0];
#pragma unroll
        for (int i = 0; i < 4; i++) acc2[i] = fmaf(a, w[i], acc2[i]);
    }
#pragma unroll
    for (int i = 0; i < 4; i++) acc2[i] = fmaxf(acc2[i], 0.0f);

    // stage bf16 transpose tile in LDS
#pragma unroll
    for (int i = 0; i < 4; i++) hs[c0 + i][n] = f2bf(acc2[i]);

    float pu = 0.0f, pv = 0.0f;
#pragma unroll
    for (int i = 0; i < 4; i++) {
        pu = fmaf(acc2[i], Wa[c0 + i], pu);
        pv = fmaf(acc2[i], Wa[CC + c0 + i], pv);
    }
    pu += __shfl_down(pu, 8, 16); pv += __shfl_down(pv, 8, 16);
    pu += __shfl_down(pu, 4, 16); pv += __shfl_down(pv, 4, 16);
    pu += __shfl_down(pu, 2, 16); pv += __shfl_down(pv, 2, 16);
    pu += __shfl_down(pu, 1, 16); pv += __shfl_down(pv, 1, 16);

    const int grow = row0 + n;
    if (cg == 0) { u[grow] = pu + ba[0]; v[grow] = pv; }

    __syncthreads();
    // coalesced hT write: 128 threads x short8 (16B), 2 per channel row
    if (t < 128) {
        const int c  = t >> 1;
        const int hf = t & 1;
        const int b   = row0 >> 12;
        const int nn0 = row0 & (NN - 1);
        *(short8*)(hT + ((size_t)(b * CC + c)) * NN + nn0 + hf * 8) =
            *(const short8*)&hs[c][hf * 8];
    }
}

// ---------------------------------------------------------------------------
// attn_v3: FUSED rowsum + attention. Block = 16 rows x FULL 4096 j
// (4 waves x 1024-col chunk each). Grid 512 -> 2 blocks/CU, 8 waves/CU.
// Phase 1: per-wave row sums over its chunk (cold HBM read of adj, fills L3).
// Phase 2: re-read adj (L3 hit), normalize, write aout (nontemporal so it
//          doesn't evict adj), bf16 MFMA accumulate h_out across all j,
//          cross-wave LDS reduce -> DIRECT store (no atomics, no memset).
// Explicit 2-stage software pipeline with named registers so the compiler
// keeps ~13KB/wave of loads in flight (attn_v2's VGPR=32 => ~2 in flight).
// ---------------------------------------------------------------------------
__global__ __launch_bounds__(256, 2) void attn_v3(
    const float* __restrict__ adj, const float* __restrict__ u,
    const float* __restrict__ v, const short* __restrict__ hT,
    float* __restrict__ hout, float* __restrict__ aout)
{
    __shared__ float red[4][16][CC + 1];   // 16.6 KB
    __shared__ float rsum[4][16];
    __shared__ float rinv[16];

    const int wave = threadIdx.x >> 6;
    const int lane = threadIdx.x & 63;
    const int row0 = blockIdx.x * 16;
    const int b  = row0 >> 12;
    const int n0 = row0 & (NN - 1);
    const float* vb = v + b * NN;
    const int jw = wave * 1024;            // this wave's column chunk

    // ---------------- phase 1: row sums over [jw, jw+1024) ----------------
    float psum[16];
    {
        floatx4 vA = *(const floatx4*)(vb + jw +       lane * 4);
        floatx4 vB = *(const floatx4*)(vb + jw + 256 + lane * 4);
        floatx4 vC = *(const floatx4*)(vb + jw + 512 + lane * 4);
        floatx4 vD = *(const floatx4*)(vb + jw + 768 + lane * 4);
#pragma unroll 4
        for (int r = 0; r < 16; ++r) {
            const float* ar = adj + ((size_t)(b * NN + n0 + r)) * NN + jw;
            floatx4 aA = *(const floatx4*)(ar +       lane * 4);
            floatx4 aB = *(const floatx4*)(ar + 256 + lane * 4);
            floatx4 aC = *(const floatx4*)(ar + 512 + lane * 4);
            floatx4 aD = *(const floatx4*)(ar + 768 + lane * 4);
            const float ur = u[b * NN + n0 + r];
            float p = 0.f;
#pragma unroll
            for (int i = 0; i < 4; ++i) {
                p = fmaf(aA[i], sigf(ur + vA[i]), p);
                p = fmaf(aB[i], sigf(ur + vB[i]), p);
                p = fmaf(aC[i], sigf(ur + vC[i]), p);
                p = fmaf(aD[i], sigf(ur + vD[i]), p);
            }
            psum[r] = p;
        }
    }
#pragma unroll
    for (int off = 32; off; off >>= 1) {
#pragma unroll
        for (int r = 0; r < 16; ++r) psum[r] += __shfl_down(psum[r], off);
    }
    if (lane == 0) {
#pragma unroll
        for (int r = 0; r < 16; ++r) rsum[wave][r] = psum[r];
    }
    __syncthreads();
    if (threadIdx.x < 16) {
        const int r = threadIdx.x;
        float s = rsum[0][r] + rsum[1][r] + rsum[2][r] + rsum[3][r];
        rinv[r] = __builtin_amdgcn_rcpf(s + 1e-10f);
    }
    __syncthreads();

    // ---------------- phase 2: normalize + a@h, pipelined ----------------
    const int quad = lane >> 4;
    const int m16  = lane & 15;
    const int n    = n0 + m16;
    const size_t rowbase = ((size_t)(b * NN + n)) * NN;
    const float un    = u[b * NN + n];     // includes ba
    const float inv_r = rinv[m16];

    const float* ap_base = adj + rowbase;
    float*       op_base = aout + rowbase;
    const short* hp0 = hT + ((size_t)(b * CC +  0 + m16)) * NN;
    const short* hp1 = hT + ((size_t)(b * CC + 16 + m16)) * NN;
    const short* hp2 = hT + ((size_t)(b * CC + 32 + m16)) * NN;
    const short* hp3 = hT + ((size_t)(b * CC + 48 + m16)) * NN;

    floatx4 acc[4];
#pragma unroll
    for (int g = 0; g < 4; g++) acc[g] = (floatx4){0.f, 0.f, 0.f, 0.f};

    const int jb0 = jw + quad * 8;

    floatx4 a0A, a1A, v0A, v1A; short8 h0A, h1A, h2A, h3A;
    floatx4 a0B, a1B, v0B, v1B; short8 h0B, h1B, h2B, h3B;

#define LOADST(S, jb) { \
    a0##S = *(const floatx4*)(ap_base + (jb));      \
    a1##S = *(const floatx4*)(ap_base + (jb) + 4);  \
    v0##S = *(const floatx4*)(vb + (jb));           \
    v1##S = *(const floatx4*)(vb + (jb) + 4);       \
    h0##S = *(const short8*)(hp0 + (jb));           \
    h1##S = *(const short8*)(hp1 + (jb));           \
    h2##S = *(const short8*)(hp2 + (jb));           \
    h3##S = *(const short8*)(hp3 + (jb)); }

#define COMPST(S, jb) { \
    float av[8] = {a0##S.x, a0##S.y, a0##S.z, a0##S.w, a1##S.x, a1##S.y, a1##S.z, a1##S.w}; \
    float vv[8] = {v0##S.x, v0##S.y, v0##S.z, v0##S.w, v1##S.x, v1##S.y, v1##S.z, v1##S.w}; \
    floatx4 o0, o1; short8 af; \
    _Pragma("unroll") \
    for (int i = 0; i < 8; ++i) { \
        float s_ = av[i] * sigf(un + vv[i]) * inv_r; \
        if (i < 4) o0[i] = s_; else o1[i - 4] = s_; \
        af[i] = f2bf(s_); } \
    __builtin_nontemporal_store(o0, (floatx4*)(op_base + (jb)));     \
    __builtin_nontemporal_store(o1, (floatx4*)(op_base + (jb) + 4)); \
    acc[0] = __builtin_amdgcn_mfma_f32_16x16x32_bf16(af, h0##S, acc[0], 0, 0, 0); \
    acc[1] = __builtin_amdgcn_mfma_f32_16x16x32_bf16(af, h1##S, acc[1], 0, 0, 0); \
    acc[2] = __builtin_amdgcn_mfma_f32_16x16x32_bf16(af, h2##S, acc[2], 0, 0, 0); \
    acc[3] = __builtin_amdgcn_mfma_f32_16x16x32_bf16(af, h3##S, acc[3], 0, 0, 0); }

    LOADST(A, jb0)
    LOADST(B, jb0 + 32)
#pragma unroll
    for (int s = 0; s < 32; s += 2) {
        COMPST(A, jb0 + s * 32)
        if (s + 2 < 32) LOADST(A, jb0 + (s + 2) * 32)
        COMPST(B, jb0 + (s + 1) * 32)
        if (s + 3 < 32) LOADST(B, jb0 + (s + 3) * 32)
    }
#undef LOADST
#undef COMPST

    // C/D layout: col(m16)=channel, row(quad*4+i)=adj row. Stage to LDS.
#pragma unroll
    for (int g = 0; g < 4; g++) {
        const int c = g * 16 + m16;
#pragma unroll
        for (int i = 0; i < 4; i++)
            red[wave][quad * 4 + i][c] = acc[g][i];
    }
    __syncthreads();

    // 256 threads x 4 elems cover 16x64; sum 4 waves, DIRECT store.
#pragma unroll
    for (int e = 0; e < 4; e++) {
        const int idx = threadIdx.x * 4 + e;
        const int rr = idx >> 6;
        const int c  = idx & 63;
        float s = red[0][rr][c] + red[1][rr][c] + red[2][rr][c] + red[3][rr][c];
        hout[((size_t)(b * NN + n0 + rr)) * CC + c] = s;
    }
}

// ---------------------------------------------------------------------------
extern "C" void kernel_launch(void* const* d_in, const int* in_sizes, int n_in,
                              void* d_out, int out_size, void* d_ws, size_t ws_size,
                              hipStream_t stream) {
    (void)in_sizes; (void)n_in; (void)out_size; (void)ws_size;
    const float* x   = (const float*)d_in[0];
    const float* adj = (const float*)d_in[1];
    const float* W1  = (const float*)d_in[2];
    const float* b1  = (const float*)d_in[3];
    const float* W2  = (const float*)d_in[4];
    const float* b2  = (const float*)d_in[5];
    const float* Wa  = (const float*)d_in[6];
    const float* ba  = (const float*)d_in[7];

    float* hout = (float*)d_out;                       // [B,N,64]
    float* aout = hout + (size_t)BB * NN * CC;         // [B,N,N]

    char* ws = (char*)d_ws;
    short* hT = (short*)ws;                            // bf16 [B][64][N]
    float* u  = (float*)(ws + (size_t)BB * CC * NN * sizeof(short));
    float* vv = u + BB * NN;

    feat_v3<<<BB * NN / 16, 256, 0, stream>>>(x, W1, b1, W2, b2, Wa, ba, hT, u, vv);
    attn_v3<<<BB * NN / 16, 256, 0, stream>>>(adj, u, vv, hT, hout, aout);
}

// Round 2
// 289.682 us; speedup vs baseline: 1.0820x; 1.0357x over previous
//
#include <hip/hip_runtime.h>

#define BB 2
#define NN 4096
#define CIN 128
#define CC 64
#define JT 256                 // j-tile width for phase B
#define NTILES (NN / JT)       // 16

typedef __attribute__((ext_vector_type(4))) float floatx4;
typedef __attribute__((ext_vector_type(8))) short short8;
typedef __attribute__((ext_vector_type(4))) short short4v;

__device__ __forceinline__ short f2bf(float f) {
    unsigned u = __float_as_uint(f);
    u += 0x7fffu + ((u >> 16) & 1u);   // RNE
    return (short)(u >> 16);
}

// sigmoid via v_exp_f32 + v_rcp_f32 (avoid precise-division expansion)
__device__ __forceinline__ float sigf(float x) {
    return __builtin_amdgcn_rcpf(1.0f + __expf(-x));
}

// lgkm-only barrier: ds_writes visible, but vmcnt NOT drained -> NT stores
// and prefetched global loads stay in flight across the barrier (m97 fix).
__device__ __forceinline__ void lbar() {
    asm volatile("s_waitcnt lgkmcnt(0)" ::: "memory");
    __builtin_amdgcn_s_barrier();
}

// ---------------------------------------------------------------------------
// feat_v3: h = relu(relu(x@W1+b1)@W2+b2); u,v scalars; hT bf16 transposed.
// 16 rows/block, 256 threads, grid 512. hT written via LDS transpose tile
// -> coalesced short8 stores.
// ---------------------------------------------------------------------------
__global__ __launch_bounds__(256) void feat_v3(
    const float* __restrict__ x, const float* __restrict__ W1,
    const float* __restrict__ b1, const float* __restrict__ W2,
    const float* __restrict__ b2, const float* __restrict__ Wa,
    const float* __restrict__ ba,
    short* __restrict__ hT, float* __restrict__ u, float* __restrict__ v)
{
    __shared__ float W1s[CIN * CC];      // 32KB
    __shared__ float W2s[CC * CC];       // 16KB
    __shared__ float xs[16 * 132];       // 8.4KB padded
    __shared__ float h1s[16 * 68];       // 4.4KB padded
    __shared__ __align__(16) short hs[CC][16];  // 2KB bf16 transpose tile

    const int t = threadIdx.x;
    const int row0 = blockIdx.x * 16;

    {
        const floatx4* s1 = (const floatx4*)W1;
        floatx4* d1 = (floatx4*)W1s;
        for (int i = t; i < CIN * CC / 4; i += 256) d1[i] = s1[i];
        const floatx4* s2 = (const floatx4*)W2;
        floatx4* d2 = (floatx4*)W2s;
        for (int i = t; i < CC * CC / 4; i += 256) d2[i] = s2[i];
        const floatx4* sx = (const floatx4*)(x + (size_t)row0 * CIN);
        for (int i = t; i < 16 * CIN / 4; i += 256) {
            int rw = i >> 5, c4 = i & 31;
            *(floatx4*)(xs + rw * 132 + c4 * 4) = sx[i];
        }
    }
    __syncthreads();

    const int n  = t >> 4;       // 0..15 local row
    const int cg = t & 15;
    const int c0 = cg * 4;

    float acc[4];
#pragma unroll
    for (int i = 0; i < 4; i++) acc[i] = b1[c0 + i];
    for (int k = 0; k < CIN; k++) {
        float a = xs[n * 132 + k];
        const floatx4 w = *(const floatx4*)&W1s[k * CC + c0];
#pragma unroll
        for (int i = 0; i < 4; i++) acc[i] = fmaf(a, w[i], acc[i]);
    }
#pragma unroll
    for (int i = 0; i < 4; i++) h1s[n * 68 + c0 + i] = fmaxf(acc[i], 0.0f);
    __syncthreads();

    float acc2[4];
#pragma unroll
    for (int i = 0; i < 4; i++) acc2[i] = b2[c0 + i];
    for (int k = 0; k < CC; k++) {
        float a = h1s[n * 68 + k];
        const floatx4 w = *(const floatx4*)&W2s[k * CC + c0];
#pragma unroll
        for (int i = 0; i < 4; i++) acc2[i] = fmaf(a, w[i], acc2[i]);
    }
#pragma unroll
    for (int i = 0; i < 4; i++) acc2[i] = fmaxf(acc2[i], 0.0f);

    // stage bf16 transpose tile in LDS
#pragma unroll
    for (int i = 0; i < 4; i++) hs[c0 + i][n] = f2bf(acc2[i]);

    float pu = 0.0f, pv = 0.0f;
#pragma unroll
    for (int i = 0; i < 4; i++) {
        pu = fmaf(acc2[i], Wa[c0 + i], pu);
        pv = fmaf(acc2[i], Wa[CC + c0 + i], pv);
    }
    pu += __shfl_down(pu, 8, 16); pv += __shfl_down(pv, 8, 16);
    pu += __shfl_down(pu, 4, 16); pv += __shfl_down(pv, 4, 16);
    pu += __shfl_down(pu, 2, 16); pv += __shfl_down(pv, 2, 16);
    pu += __shfl_down(pu, 1, 16); pv += __shfl_down(pv, 1, 16);

    const int grow = row0 + n;
    if (cg == 0) { u[grow] = pu + ba[0]; v[grow] = pv; }

    __syncthreads();
    // coalesced hT write: 128 threads x short8 (16B), 2 per channel row
    if (t < 128) {
        const int c  = t >> 1;
        const int hf = t & 1;
        const int b   = row0 >> 12;
        const int nn0 = row0 & (NN - 1);
        *(short8*)(hT + ((size_t)(b * CC + c)) * NN + nn0 + hf * 8) =
            *(const short8*)&hs[c][hf * 8];
    }
}

// ---------------------------------------------------------------------------
// attn_v4: fused rowsum + attention, GEMM-ified.
// Block = 16 rows x all 4096 j, 512 threads (8 waves), grid 512
//   -> 2 blocks/CU, 16 waves/CU (2x attn_v3's occupancy).
// Phase A: wave w owns rows 2w,2w+1; full-row sums with contiguous 1KB/instr
//   reads (proven rowsum pattern). No cross-wave reduce; 1/r kept in regs.
// Phase B: per 256-col tile: wave computes s for its 2 rows CONTIGUOUSLY
//   (coalesced adj read from L3, coalesced NT aout store), packs bf16 P into
//   double-buffered LDS; then MFMA phase: wave (c-group, k-half) reads
//   A-frags from LDS (row=lane&15, k=(lane>>4)*8+i, same layout as v2's af),
//   B-frags from hT (L2-resident). One lgkm-only barrier per tile.
// Epilogue: pairwise wave add in LDS, direct hout store. No atomics.
// ---------------------------------------------------------------------------
__global__ __launch_bounds__(512, 4) void attn_v4(
    const float* __restrict__ adj, const float* __restrict__ u,
    const float* __restrict__ v, const short* __restrict__ hT,
    float* __restrict__ hout, float* __restrict__ aout)
{
    __shared__ __align__(16) short P[2][16][264];  // 16.9KB, stride 528B
    __shared__ float red[4][16][17];               // 4.3KB epilogue

    const int wave = threadIdx.x >> 6;   // 0..7
    const int lane = threadIdx.x & 63;
    const int quad = lane >> 4;
    const int m16  = lane & 15;

    const int row0 = blockIdx.x * 16;
    const int b  = row0 >> 12;
    const int n0 = row0 & (NN - 1);
    const float* vb = v + b * NN;

    // rows owned by this wave for rowsum + sigmoid/normalize
    const int r0 = 2 * wave;
    const float u0 = u[b * NN + n0 + r0];
    const float u1 = u[b * NN + n0 + r0 + 1];
    const float* a0p = adj + ((size_t)(b * NN + n0 + r0)) * NN;
    const float* a1p = a0p + NN;
    float* o0p = aout + ((size_t)(b * NN + n0 + r0)) * NN;
    float* o1p = o0p + NN;

    // ---------------- phase A: full-row sums (contiguous streams) --------
    float s0 = 0.f, s1 = 0.f;
#pragma unroll 4
    for (int c = 0; c < 16; ++c) {
        const int j = c * 256 + lane * 4;
        const floatx4 va = *(const floatx4*)(vb + j);
        const floatx4 aa = *(const floatx4*)(a0p + j);
        const floatx4 ab = *(const floatx4*)(a1p + j);
#pragma unroll
        for (int i = 0; i < 4; ++i) {
            s0 = fmaf(aa[i], sigf(u0 + va[i]), s0);
            s1 = fmaf(ab[i], sigf(u1 + va[i]), s1);
        }
    }
#pragma unroll
    for (int off = 32; off; off >>= 1) {
        s0 += __shfl_down(s0, off);
        s1 += __shfl_down(s1, off);
    }
    s0 = __shfl(s0, 0);
    s1 = __shfl(s1, 0);
    const float ir0 = __builtin_amdgcn_rcpf(s0 + 1e-10f);
    const float ir1 = __builtin_amdgcn_rcpf(s1 + 1e-10f);

    // ---------------- phase B: normalize + P-tile + MFMA ------------------
    const int c0 = (wave & 3) * 16;      // this wave's output channel group
    const int kh = wave >> 2;            // k-half (0: ks 0-3, 1: ks 4-7)
    const short* hp = hT + ((size_t)(b * CC + c0 + m16)) * NN;

    floatx4 acc = (floatx4){0.f, 0.f, 0.f, 0.f};

#define FILL(T, BUF) { \
    const int j = (T) * JT + lane * 4; \
    const floatx4 va = *(const floatx4*)(vb + j); \
    const floatx4 aa = *(const floatx4*)(a0p + j); \
    const floatx4 ab = *(const floatx4*)(a1p + j); \
    floatx4 o0, o1; short4v pk0, pk1; \
    _Pragma("unroll") \
    for (int i = 0; i < 4; ++i) { \
        float sA = aa[i] * sigf(u0 + va[i]) * ir0; \
        float sB = ab[i] * sigf(u1 + va[i]) * ir1; \
        o0[i] = sA; o1[i] = sB; \
        pk0[i] = f2bf(sA); pk1[i] = f2bf(sB); } \
    __builtin_nontemporal_store(o0, (floatx4*)(o0p + j)); \
    __builtin_nontemporal_store(o1, (floatx4*)(o1p + j)); \
    *(short4v*)&P[BUF][r0][lane * 4]     = pk0; \
    *(short4v*)&P[BUF][r0 + 1][lane * 4] = pk1; }

#define MM(T, BUF) { \
    const short* hpt = hp + (size_t)(T) * JT; \
    _Pragma("unroll") \
    for (int ks = 0; ks < 4; ++ks) { \
        const int kk = kh * 4 + ks; \
        const short8 Af = *(const short8*)&P[BUF][m16][kk * 32 + quad * 8]; \
        const short8 Bf = *(const short8*)(hpt + kk * 32 + quad * 8); \
        acc = __builtin_amdgcn_mfma_f32_16x16x32_bf16(Af, Bf, acc, 0, 0, 0); \
    } }

    FILL(0, 0)
    lbar();
#pragma unroll 2
    for (int t = 0; t < NTILES; ++t) {
        if (t + 1 < NTILES) { FILL(t + 1, (t + 1) & 1) }
        MM(t, t & 1)
        lbar();
    }
#undef FILL
#undef MM

    // ---------------- epilogue: pair (w, w+4) add, direct store ----------
    if (kh == 1) {
#pragma unroll
        for (int i = 0; i < 4; ++i) red[wave - 4][quad * 4 + i][m16] = acc[i];
    }
    __syncthreads();
    if (kh == 0) {
#pragma unroll
        for (int i = 0; i < 4; ++i) {
            const float sfin = acc[i] + red[wave][quad * 4 + i][m16];
            hout[((size_t)(b * NN + n0 + quad * 4 + i)) * CC + c0 + m16] = sfin;
        }
    }
}

// ---------------------------------------------------------------------------
extern "C" void kernel_launch(void* const* d_in, const int* in_sizes, int n_in,
                              void* d_out, int out_size, void* d_ws, size_t ws_size,
                              hipStream_t stream) {
    (void)in_sizes; (void)n_in; (void)out_size; (void)ws_size;
    const float* x   = (const float*)d_in[0];
    const float* adj = (const float*)d_in[1];
    const float* W1  = (const float*)d_in[2];
    const float* b1  = (const float*)d_in[3];
    const float* W2  = (const float*)d_in[4];
    const float* b2  = (const float*)d_in[5];
    const float* Wa  = (const float*)d_in[6];
    const float* ba  = (const float*)d_in[7];

    float* hout = (float*)d_out;                       // [B,N,64]
    float* aout = hout + (size_t)BB * NN * CC;         // [B,N,N]

    char* ws = (char*)d_ws;
    short* hT = (short*)ws;                            // bf16 [B][64][N]
    float* u  = (float*)(ws + (size_t)BB * CC * NN * sizeof(short));
    float* vv = u + BB * NN;

    feat_v3<<<BB * NN / 16, 256, 0, stream>>>(x, W1, b1, W2, b2, Wa, ba, hT, u, vv);
    attn_v4<<<BB * NN / 16, 512, 0, stream>>>(adj, u, vv, hT, hout, aout);
}